// Round 4
// baseline (43464.163 us; speedup 1.0000x reference)
//
#include <hip/hip_runtime.h>

// Problem constants
#define HH    1024
#define DD    256
#define BSB   1024
#define TT    256
#define N3H   3072   // 3*H
#define CAT1  32
#define CAT2E 47

#define NB    256    // persistent grid: 1 block/CU, co-residency guaranteed
#define NTH   256

typedef unsigned short u16;
typedef short bf16x8 __attribute__((ext_vector_type(8)));
typedef float f32x4  __attribute__((ext_vector_type(4)));

__device__ __forceinline__ u16 f2bf(float f) {
  unsigned int x = __float_as_uint(f);
  unsigned int lsb = (x >> 16) & 1u;
  x += 0x7fffu + lsb;
  return (u16)(x >> 16);
}

// async global->LDS, 16B per lane; LDS dest is wave-uniform base + lane*16
__device__ __forceinline__ void gload_lds16(const u16* src, u16* lds) {
  __builtin_amdgcn_global_load_lds(
      (const __attribute__((address_space(1))) void*)src,
      (__attribute__((address_space(3))) void*)lds, 16, 0, 0);
}

// ---------------------------------------------------------------------------
// Grid barrier (multi-flag): block b release-stores phase id pc to its own
// cacheline; block 0 polls all NB flags then release-bumps gen; all blocks
// relaxed-spin on gen + acquire fence. Flags zeroed by prep_state each run
// (graph replay safe); pc is monotonically increasing within a run.
// ---------------------------------------------------------------------------
__device__ __forceinline__ void gbar(unsigned* flags, unsigned* gen, unsigned pc)
{
  __syncthreads();
  if (threadIdx.x == 0) {
    __threadfence();   // release: make this block's writes agent-visible
    __hip_atomic_store(&flags[blockIdx.x * 32], pc, __ATOMIC_RELAXED,
                       __HIP_MEMORY_SCOPE_AGENT);
  }
  if (blockIdx.x == 0) {
    // NB == NTH: each thread polls exactly one flag
    while (__hip_atomic_load(&flags[threadIdx.x * 32], __ATOMIC_RELAXED,
                             __HIP_MEMORY_SCOPE_AGENT) < pc)
      __builtin_amdgcn_s_sleep(1);
    __syncthreads();
    if (threadIdx.x == 0)
      __hip_atomic_store(gen, pc, __ATOMIC_RELEASE, __HIP_MEMORY_SCOPE_AGENT);
  }
  if (threadIdx.x == 0) {
    while (__hip_atomic_load(gen, __ATOMIC_RELAXED,
                             __HIP_MEMORY_SCOPE_AGENT) < pc)
      __builtin_amdgcn_s_sleep(2);
    __threadfence();   // acquire: invalidate stale L1/L2 before reading peers' data
  }
  __syncthreads();
}

// ---------------------------------------------------------------------------
// GEMM tile body (proven in R1-R3): C[128,128] tile at (tx,ty).
// C = A[M,K] @ B[N,K]^T (+bias) (+addend); act=1 -> fused head activation.
// BK=64, 4 waves, 2-deep dbuf, counted vmcnt, XOR-swizzled linear LDS.
// mfma_f32_16x16x32_bf16 layouts (HW-verified m89/m91).
// ---------------------------------------------------------------------------
__device__ void gemm_tile(int tx, int ty,
                          const u16* A, int lda, int K,
                          const u16* B, int ldb,
                          float* C, int ldc,
                          const float* bias, const float* addend,
                          float* out, u16* xout, int tstep, int act,
                          u16* lds)
{
  const int colBase = tx * 128;
  const int rowBase = ty * 128;

  u16* As = lds;            // [2][128*64]
  u16* Bs = lds + 16384;

  const int tid  = threadIdx.x;
  const int wave = tid >> 6;
  const int lane = tid & 63;
  const int q    = lane >> 4;
  const int l16  = lane & 15;
  const int waveRow = (wave >> 1) * 64;
  const int waveCol = (wave & 1) * 64;

  const int  srow = wave * 8 + (lane >> 3);
  const int  sswz = ((lane & 7) ^ (lane >> 3)) << 3;
  const u16* aptr = A + (size_t)(rowBase + srow) * lda + sswz;
  const u16* bptr = B + (size_t)(colBase + srow) * ldb + sswz;
  const size_t astep = (size_t)32 * lda;
  const size_t bstep = (size_t)32 * ldb;
  const int ldoff = wave << 9;

  f32x4 acc[4][4];
  #pragma unroll
  for (int i = 0; i < 4; ++i)
    #pragma unroll
    for (int j = 0; j < 4; ++j)
      acc[i][j] = (f32x4){0.f, 0.f, 0.f, 0.f};

  const int nk = K >> 6;

  #pragma unroll
  for (int i = 0; i < 4; ++i) {
    gload_lds16(aptr + (size_t)i * astep, &As[ldoff + (i << 11)]);
    gload_lds16(bptr + (size_t)i * bstep, &Bs[ldoff + (i << 11)]);
  }
  #pragma unroll
  for (int i = 0; i < 4; ++i) {
    gload_lds16(aptr + 64 + (size_t)i * astep, &As[8192 + ldoff + (i << 11)]);
    gload_lds16(bptr + 64 + (size_t)i * bstep, &Bs[8192 + ldoff + (i << 11)]);
  }

  for (int k = 0; k < nk; ++k) {
    const int cb = (k & 1) << 13;
    if (k < nk - 1) {
      asm volatile("s_waitcnt vmcnt(8)" ::: "memory");
    } else {
      asm volatile("s_waitcnt vmcnt(0)" ::: "memory");
    }
    __builtin_amdgcn_s_barrier();
    __builtin_amdgcn_sched_barrier(0);

    #pragma unroll
    for (int ks = 0; ks < 2; ++ks) {
      bf16x8 af[4], bfr[4];
      const int kb = (ks << 2) + q;
      #pragma unroll
      for (int mi = 0; mi < 4; ++mi) {
        int r = waveRow + mi * 16 + l16;
        af[mi] = *(const bf16x8*)&As[cb + (r << 6) + ((kb ^ (l16 & 7)) << 3)];
      }
      #pragma unroll
      for (int ni = 0; ni < 4; ++ni) {
        int r = waveCol + ni * 16 + l16;
        bfr[ni] = *(const bf16x8*)&Bs[cb + (r << 6) + ((kb ^ (l16 & 7)) << 3)];
      }
      #pragma unroll
      for (int mi = 0; mi < 4; ++mi)
        #pragma unroll
        for (int ni = 0; ni < 4; ++ni)
          acc[mi][ni] = __builtin_amdgcn_mfma_f32_16x16x32_bf16(af[mi], bfr[ni], acc[mi][ni], 0, 0, 0);
    }

    __builtin_amdgcn_sched_barrier(0);
    __builtin_amdgcn_s_barrier();
    __builtin_amdgcn_sched_barrier(0);
    if (k + 2 < nk) {
      const int k2 = (k + 2) << 6;
      #pragma unroll
      for (int i = 0; i < 4; ++i) {
        gload_lds16(aptr + k2 + (size_t)i * astep, &As[cb + ldoff + (i << 11)]);
        gload_lds16(bptr + k2 + (size_t)i * bstep, &Bs[cb + ldoff + (i << 11)]);
      }
    }
  }

  if (act) {
    const bool smWave = (colBase + waveCol) == 0;
    #pragma unroll
    for (int mi = 0; mi < 4; ++mi) {
      #pragma unroll
      for (int r = 0; r < 4; ++r) {
        const int row = rowBase + waveRow + mi * 16 + q * 4 + r;
        float v[4];
        #pragma unroll
        for (int ni = 0; ni < 4; ++ni)
          v[ni] = acc[mi][ni][r] + bias[colBase + waveCol + ni * 16 + l16];
        float res[4];
        if (smWave) {
          float m1 = fmaxf(v[0], v[1]);
          #pragma unroll
          for (int msk = 1; msk < 16; msk <<= 1) m1 = fmaxf(m1, __shfl_xor(m1, msk));
          float e0 = expf(v[0] - m1), e1 = expf(v[1] - m1);
          float s1 = e0 + e1;
          #pragma unroll
          for (int msk = 1; msk < 16; msk <<= 1) s1 += __shfl_xor(s1, msk);
          res[0] = e0 / s1;
          res[1] = e1 / s1;
          float mv = (l16 < 15) ? v[2] : -1e30f;
          #pragma unroll
          for (int msk = 1; msk < 16; msk <<= 1) mv = fmaxf(mv, __shfl_xor(mv, msk));
          float e2 = expf(v[2] - mv);
          float sv = (l16 < 15) ? e2 : 0.f;
          #pragma unroll
          for (int msk = 1; msk < 16; msk <<= 1) sv += __shfl_xor(sv, msk);
          res[2] = (l16 < 15) ? (e2 / sv) : (1.f / (1.f + expf(-v[2])));
          res[3] = 1.f / (1.f + expf(-v[3]));
        } else {
          #pragma unroll
          for (int ni = 0; ni < 4; ++ni)
            res[ni] = 1.f / (1.f + expf(-v[ni]));
        }
        #pragma unroll
        for (int ni = 0; ni < 4; ++ni) {
          const int col = colBase + waveCol + ni * 16 + l16;
          out[((size_t)row * TT + tstep) * DD + col] = res[ni];
          xout[row * DD + col] = f2bf(res[ni]);
        }
      }
    }
    return;
  }

  #pragma unroll
  for (int mi = 0; mi < 4; ++mi) {
    #pragma unroll
    for (int ni = 0; ni < 4; ++ni) {
      #pragma unroll
      for (int r = 0; r < 4; ++r) {
        int row = rowBase + waveRow + mi * 16 + q * 4 + r;
        int col = colBase + waveCol + ni * 16 + l16;
        float v = acc[mi][ni][r];
        if (bias)   v += bias[col];
        if (addend) v += addend[(size_t)row * ldc + col];
        C[(size_t)row * ldc + col] = v;
      }
    }
  }
}

// ---------------------------------------------------------------------------
// GRU gate phase (grid-stride, float4): hn = (1-z)*n + z*h
// ---------------------------------------------------------------------------
__device__ __forceinline__ float gate1f(float gir, float ghr, float giz, float ghz,
                                        float gin, float ghn, float hv) {
  float r = 1.f / (1.f + expf(-(gir + ghr)));
  float z = 1.f / (1.f + expf(-(giz + ghz)));
  float n = tanhf(gin + r * ghn);
  return (1.f - z) * n + z * hv;
}

__device__ void gate_phase(const float4* GI, const float4* GH,
                           float4* h, ushort4* hbf)
{
  const int nth = NB * NTH;
  for (int idx = blockIdx.x * NTH + threadIdx.x; idx < BSB * HH / 4; idx += nth) {
    int b = idx >> 8, m = idx & 255;
    size_t base = (size_t)b * 768;
    float4 gir = GI[base + m], giz = GI[base + 256 + m], gin = GI[base + 512 + m];
    float4 ghr = GH[base + m], ghz = GH[base + 256 + m], ghn = GH[base + 512 + m];
    float4 hv = h[idx];
    float4 hn;
    hn.x = gate1f(gir.x, ghr.x, giz.x, ghz.x, gin.x, ghn.x, hv.x);
    hn.y = gate1f(gir.y, ghr.y, giz.y, ghz.y, gin.y, ghn.y, hv.y);
    hn.z = gate1f(gir.z, ghr.z, giz.z, ghz.z, gin.z, ghn.z, hv.z);
    hn.w = gate1f(gir.w, ghr.w, giz.w, ghz.w, gin.w, ghn.w, hv.w);
    h[idx] = hn;
    ushort4 hb;
    hb.x = f2bf(hn.x); hb.y = f2bf(hn.y); hb.z = f2bf(hn.z); hb.w = f2bf(hn.w);
    hbf[idx] = hb;
  }
}

// ---------------------------------------------------------------------------
// Persistent kernel: prologue + all T steps, phases separated by gbar.
// ---------------------------------------------------------------------------
struct P {
  const u16 *Wih0, *Whh0, *Wih1, *Whh1, *Wfc;
  const u16 *glob;
  u16 *x;                       // xbf
  float *h0f, *h1f; u16 *h0b, *h1b;
  float *Gglob, *GI, *GH0, *GH1;
  const float *b_ih0, *b_hh0, *b_ih1, *b_hh1, *b_fc;
  float *out;
  unsigned *flags, *gen;
};

__global__ __launch_bounds__(NTH, 1) void persist(P p)
{
  __shared__ __align__(16) u16 lds[32768];   // 64 KiB
  const int bid = blockIdx.x;
  unsigned pc = 1;

  // PRE0: Gglob = glob @ Wih0[:, :H]^T + b_ih0  ||  GH0(0) = h0 @ Whh0^T + b_hh0
  for (int j = bid; j < 384; j += NB) {
    if (j < 192)
      gemm_tile(j % 24, j / 24, p.glob, HH, HH, p.Wih0, 1280,
                p.Gglob, N3H, p.b_ih0, nullptr, nullptr, nullptr, 0, 0, lds);
    else
      gemm_tile((j - 192) % 24, (j - 192) / 24, p.h0b, HH, HH, p.Whh0, HH,
                p.GH0, N3H, p.b_hh0, nullptr, nullptr, nullptr, 0, 0, lds);
  }
  gbar(p.flags, p.gen, pc); ++pc;

  // PRE1: GI0(0) = x0 @ Wih0[:, H:]^T + Gglob  ||  GH1(0) = h1 @ Whh1^T + b_hh1
  for (int j = bid; j < 384; j += NB) {
    if (j < 192)
      gemm_tile(j % 24, j / 24, p.x, DD, DD, p.Wih0 + HH, 1280,
                p.GI, N3H, nullptr, p.Gglob, nullptr, nullptr, 0, 0, lds);
    else
      gemm_tile((j - 192) % 24, (j - 192) / 24, p.h1b, HH, HH, p.Whh1, HH,
                p.GH1, N3H, p.b_hh1, nullptr, nullptr, nullptr, 0, 0, lds);
  }
  gbar(p.flags, p.gen, pc); ++pc;

  for (int t = 0; t < TT; ++t) {
    const bool last = (t == TT - 1);

    // PH_GATE0: h0 = gate(GI0, GH0)
    gate_phase((const float4*)p.GI, (const float4*)p.GH0,
               (float4*)p.h0f, (ushort4*)p.h0b);
    gbar(p.flags, p.gen, pc); ++pc;

    // PH_B: GI1 = h0 @ Wih1^T + b_ih1  ||  GH0(t+1) = h0 @ Whh0^T + b_hh0
    for (int j = bid; j < 384; j += NB) {
      if (j < 192)
        gemm_tile(j % 24, j / 24, p.h0b, HH, HH, p.Wih1, HH,
                  p.GI, N3H, p.b_ih1, nullptr, nullptr, nullptr, 0, 0, lds);
      else if (!last)
        gemm_tile((j - 192) % 24, (j - 192) / 24, p.h0b, HH, HH, p.Whh0, HH,
                  p.GH0, N3H, p.b_hh0, nullptr, nullptr, nullptr, 0, 0, lds);
    }
    gbar(p.flags, p.gen, pc); ++pc;

    // PH_GATE1: h1 = gate(GI1, GH1)
    gate_phase((const float4*)p.GI, (const float4*)p.GH1,
               (float4*)p.h1f, (ushort4*)p.h1b);
    gbar(p.flags, p.gen, pc); ++pc;

    // PH_C: head+act -> out[:,t,:], xbf  ||  GH1(t+1) = h1 @ Whh1^T + b_hh1
    if (bid < 16)
      gemm_tile(bid % 2, bid / 2, p.h1b, HH, HH, p.Wfc, HH,
                nullptr, DD, p.b_fc, nullptr, p.out, p.x, t, 1, lds);
    else if (bid >= 64 && !last)
      gemm_tile((bid - 64) % 24, (bid - 64) / 24, p.h1b, HH, HH, p.Whh1, HH,
                p.GH1, N3H, p.b_hh1, nullptr, nullptr, nullptr, 0, 0, lds);
    gbar(p.flags, p.gen, pc); ++pc;

    // PH_D: GI0(t+1) = x(t+1) @ Wih0[:, H:]^T + Gglob
    if (!last) {
      if (bid < 192)
        gemm_tile(bid % 24, bid / 24, p.x, DD, DD, p.Wih0 + HH, 1280,
                  p.GI, N3H, nullptr, p.Gglob, nullptr, nullptr, 0, 0, lds);
      gbar(p.flags, p.gen, pc); ++pc;
    }
  }
}

// ---------------------------------------------------------------------------
// Prep: fp32 -> bf16 weight conversion; state init; barrier-flag zeroing
// ---------------------------------------------------------------------------
__global__ void convert_kernel(const float* __restrict__ src, u16* __restrict__ dst, int n)
{
  int i = blockIdx.x * blockDim.x + threadIdx.x;
  if (i < n) dst[i] = f2bf(src[i]);
}

__global__ void prep_state(const float* __restrict__ embed, const float* __restrict__ dyn,
                           u16* __restrict__ globbf,
                           float* __restrict__ h0, u16* __restrict__ h0bf,
                           float* __restrict__ h1, u16* __restrict__ h1bf,
                           u16* __restrict__ xbf, unsigned* __restrict__ barr)
{
  int idx = blockIdx.x * blockDim.x + threadIdx.x;  // 1M
  int b = idx >> 10, j = idx & 1023;
  const float* e = embed + (size_t)b * 3072;
  globbf[idx] = f2bf(e[j]);
  float v0 = e[1024 + j]; h0[idx] = v0; h0bf[idx] = f2bf(v0);
  float v1 = e[2048 + j]; h1[idx] = v1; h1bf[idx] = f2bf(v1);
  if (j < DD) {
    xbf[b * DD + j] = f2bf(dyn[(size_t)b * (TT * DD) + j]);  // x0
  }
  if (idx < 16384) barr[idx] = 0;  // flags (256*32) + gen — every replay
}

// ---------------------------------------------------------------------------
extern "C" void kernel_launch(void* const* d_in, const int* in_sizes, int n_in,
                              void* d_out, int out_size, void* d_ws, size_t ws_size,
                              hipStream_t stream)
{
  const float* embed = (const float*)d_in[0];
  const float* dyn   = (const float*)d_in[1];
  // d_in[2] = seq_len (256, hardcoded)
  const float* W_ih0 = (const float*)d_in[3];
  const float* W_hh0 = (const float*)d_in[4];
  const float* b_ih0 = (const float*)d_in[5];
  const float* b_hh0 = (const float*)d_in[6];
  const float* W_ih1 = (const float*)d_in[7];
  const float* W_hh1 = (const float*)d_in[8];
  const float* b_ih1 = (const float*)d_in[9];
  const float* b_hh1 = (const float*)d_in[10];
  const float* W_fc  = (const float*)d_in[11];
  const float* b_fc  = (const float*)d_in[12];
  float* out = (float*)d_out;

  char* ws = (char*)d_ws;
  size_t off = 0;
  auto carve = [&](size_t bytes) -> void* {
    void* p = ws + off;
    off += (bytes + 255) & ~(size_t)255;
    return p;
  };
  u16* Wih0b = (u16*)carve((size_t)N3H * 1280 * 2);
  u16* Whh0b = (u16*)carve((size_t)N3H * HH * 2);
  u16* Wih1b = (u16*)carve((size_t)N3H * HH * 2);
  u16* Whh1b = (u16*)carve((size_t)N3H * HH * 2);
  u16* Wfcb  = (u16*)carve((size_t)DD * HH * 2);
  u16* globb = (u16*)carve((size_t)BSB * HH * 2);
  u16* xbf   = (u16*)carve((size_t)BSB * DD * 2);
  float* h0f = (float*)carve((size_t)BSB * HH * 4);
  float* h1f = (float*)carve((size_t)BSB * HH * 4);
  u16* h0b   = (u16*)carve((size_t)BSB * HH * 2);
  u16* h1b   = (u16*)carve((size_t)BSB * HH * 2);
  float* Gglob = (float*)carve((size_t)BSB * N3H * 4);
  float* GI    = (float*)carve((size_t)BSB * N3H * 4);
  float* GH0f  = (float*)carve((size_t)BSB * N3H * 4);
  float* GH1f  = (float*)carve((size_t)BSB * N3H * 4);
  unsigned* barr = (unsigned*)carve((size_t)16384 * 4);
  (void)ws_size;

  {
    int n;
    n = N3H * 1280; convert_kernel<<<(n + 255) / 256, 256, 0, stream>>>(W_ih0, Wih0b, n);
    n = N3H * HH;   convert_kernel<<<(n + 255) / 256, 256, 0, stream>>>(W_hh0, Whh0b, n);
    n = N3H * HH;   convert_kernel<<<(n + 255) / 256, 256, 0, stream>>>(W_ih1, Wih1b, n);
    n = N3H * HH;   convert_kernel<<<(n + 255) / 256, 256, 0, stream>>>(W_hh1, Whh1b, n);
    n = DD * HH;    convert_kernel<<<(n + 255) / 256, 256, 0, stream>>>(W_fc, Wfcb, n);
  }
  prep_state<<<(BSB * HH) / 256, 256, 0, stream>>>(embed, dyn, globb, h0f, h0b,
                                                   h1f, h1b, xbf, barr);

  P p;
  p.Wih0 = Wih0b; p.Whh0 = Whh0b; p.Wih1 = Wih1b; p.Whh1 = Whh1b; p.Wfc = Wfcb;
  p.glob = globb; p.x = xbf;
  p.h0f = h0f; p.h1f = h1f; p.h0b = h0b; p.h1b = h1b;
  p.Gglob = Gglob; p.GI = GI; p.GH0 = GH0f; p.GH1 = GH1f;
  p.b_ih0 = b_ih0; p.b_hh0 = b_hh0; p.b_ih1 = b_ih1; p.b_hh1 = b_hh1; p.b_fc = b_fc;
  p.out = out;
  p.flags = barr; p.gen = barr + NB * 32;

  persist<<<NB, NTH, 0, stream>>>(p);
}